// Round 12
// baseline (376.321 us; speedup 1.0000x reference)
//
#include <hip/hip_runtime.h>

typedef unsigned short u16;
typedef unsigned int u32;
typedef unsigned long long u64;
typedef __attribute__((ext_vector_type(8))) short bf16x8;
typedef __attribute__((ext_vector_type(4))) float f32x4;

#define H_ 200
#define W_ 176
#define HW_ (200 * 176)
#define D0_ 41
#define D1_ 20
#define D2_ 9
#define B_ 2

__device__ __forceinline__ u16 f2bf(float f) {
  union { float f; u32 u; } c; c.f = f;
  u32 u = c.u;
  u32 r = (u + 0x7fffu + ((u >> 16) & 1u)) >> 16;
  return (u16)r;
}

// idx0 entries are tagged: 0x55000000 | point_index. Anything else (0xAA poison,
// never-written garbage) decodes to -1. Removes the need to -1-fill idx0, which
// breaks the fill->scatter ordering dependency and lets boot be ONE kernel.
__device__ __forceinline__ int detag0(int v) {
  return (((u32)v >> 24) == 0x55u) ? (v & 0xFFFFFF) : -1;
}

struct P {
  const float* feats; const int* coors;
  const float *w0, *w1a, *w1b, *wz1, *wz2;
  const float *g0, *b0, *g1, *b1, *g2, *b2, *g3, *b3, *g4, *b4;
  int* ctrl; float* stats;
  int *idx0, *idx1, *claim2;
  int* nbr1; u32* gmask1;
  int *nbrz1, *nbrz2, *coords1, *coords2;
  float *xb0, *xb1, *xb2, *xb3, *xb4;
  u16 *fb, *wf0, *wf1a, *wf1b, *wfz1, *wfz2;
  float* out;
  uint4* fillp;   // idx1 + claim2 region (contiguous)
  int N, nfill16;
  long prepTotal;
};

// ---- weight repack: (NOFF,K,64) fp32 -> bf16 fragment order [o][ks][nt][lane][8] ----
__device__ __forceinline__ void repack1(const float* __restrict__ w, u16* __restrict__ frag,
                                        int K, int t) {
  int j = t & 7;
  int lane = (t >> 3) & 63;
  int nt = (t >> 9) & 3;
  int rest = t >> 11;
  int KS = K / 32;
  int ks = rest % KS;
  int o = rest / KS;
  int k = ks * 32 + (lane >> 4) * 8 + j;
  int n = nt * 16 + (lane & 15);
  frag[t] = f2bf(w[((size_t)o * K + k) * 64 + n]);
}

// ---- wave claim (wave 0 only): downsample for points [base, base+64) ----
// tagged != 0 -> idxin entries are 0x55-tagged (level-0 idx map)
__device__ __forceinline__ void claim_ep(int t, int base, int cnt,
                                         const int* __restrict__ coordsIn,
                                         const int* __restrict__ idxin, int Din, int Dout,
                                         int* __restrict__ claim, int* __restrict__ coords_out,
                                         int* __restrict__ nbrzN, int* __restrict__ outcnt,
                                         int tagged) {
  int i = base + t;
  bool w0 = false, w1 = false;
  int pos0 = 0, pos1 = 0, oz0 = -1, oz1 = -1;
  int b = 0, z = 0, yy = 0, xx = 0;
  if (i < cnt) {
    int4 cc = *(const int4*)(coordsIn + (size_t)i * 4);
    b = cc.x; z = cc.y; yy = cc.z; xx = cc.w;
    if (z & 1) {
      int oz = (z - 1) >> 1;
      if (oz < Dout) oz0 = oz;
    } else {
      int oz = z >> 1;
      if (oz < Dout) oz0 = oz;
      if (z >= 2) oz1 = oz - 1;
    }
    if (oz0 >= 0) {
      pos0 = ((b * Dout + oz0) * H_ + yy) * W_ + xx;
      w0 = (atomicCAS(&claim[pos0], -1, -2) == -1);
    }
    if (oz1 >= 0) {
      pos1 = ((b * Dout + oz1) * H_ + yy) * W_ + xx;
      w1 = (atomicCAS(&claim[pos1], -1, -2) == -1);
    }
  }
  u64 m0 = __ballot(w0), m1 = __ballot(w1);
  int c0 = __popcll(m0), c1 = __popcll(m1);
  int lane = t & 63;
  u64 lt = (lane == 63) ? 0x7FFFFFFFFFFFFFFFull : ((1ull << lane) - 1ull);
  int bse2 = 0;
  if (lane == 0 && (c0 + c1) > 0) bse2 = atomicAdd(outcnt, c0 + c1);
  bse2 = __shfl(bse2, 0);
  if (w0) {
    int id = bse2 + __popcll(m0 & lt);
    claim[pos0] = id;
    coords_out[id * 4 + 0] = b; coords_out[id * 4 + 1] = oz0;
    coords_out[id * 4 + 2] = yy; coords_out[id * 4 + 3] = xx;
    size_t bse = ((size_t)(b * Din + 2 * oz0) * H_ + yy) * W_ + xx;
    int v0 = idxin[bse], v1 = idxin[bse + HW_], v2 = idxin[bse + 2 * (size_t)HW_];
    nbrzN[id * 3 + 0] = tagged ? detag0(v0) : v0;
    nbrzN[id * 3 + 1] = tagged ? detag0(v1) : v1;
    nbrzN[id * 3 + 2] = tagged ? detag0(v2) : v2;
  }
  if (w1) {
    int id = bse2 + c0 + __popcll(m1 & lt);
    claim[pos1] = id;
    coords_out[id * 4 + 0] = b; coords_out[id * 4 + 1] = oz1;
    coords_out[id * 4 + 2] = yy; coords_out[id * 4 + 3] = xx;
    size_t bse = ((size_t)(b * Din + 2 * oz1) * H_ + yy) * W_ + xx;
    int v0 = idxin[bse], v1 = idxin[bse + HW_], v2 = idxin[bse + 2 * (size_t)HW_];
    nbrzN[id * 3 + 0] = tagged ? detag0(v0) : v0;
    nbrzN[id * 3 + 1] = tagged ? detag0(v1) : v1;
    nbrzN[id * 3 + 2] = tagged ? detag0(v2) : v2;
  }
}

__device__ __forceinline__ void bn_pre(const float* __restrict__ statsIn, int cntN,
                                       const float* __restrict__ gamma,
                                       const float* __restrict__ beta,
                                       float* __restrict__ ggs, float* __restrict__ bbs, int t) {
  if (t < 64) {
    float s = 0.f, q = 0.f;
#pragma unroll
    for (int k = 0; k < 4; ++k) { s += statsIn[k * 128 + t]; q += statsIn[k * 128 + 64 + t]; }
    float cf = (float)(cntN > 0 ? cntN : 1);
    float mean = s / cf;
    float var = q / cf - mean * mean;
    float inv = rsqrtf(var + 1e-3f);
    float g = gamma[t] * inv;
    ggs[t] = g;
    bbs[t] = beta[t] - mean * g;
  }
}

// raw K=64 feature row load (4 x float4); skipped when j < 0
__device__ __forceinline__ void loadRaw64(const float* __restrict__ xp, int j, int kr,
                                          float4* __restrict__ r) {
  if (j >= 0) {
    const float* src = xp + (size_t)j * 64 + kr * 8;
    r[0] = *(const float4*)(src);
    r[1] = *(const float4*)(src + 4);
    r[2] = *(const float4*)(src + 32);
    r[3] = *(const float4*)(src + 36);
  }
}

// BN+ReLU convert raw -> bf16 A-fragments; zero when j < 0
__device__ __forceinline__ void cvtA64(const float4* __restrict__ r, int j,
                                       const float* gr_, const float* br_, bf16x8* aa) {
  if (j >= 0) {
#pragma unroll
    for (int ks = 0; ks < 2; ++ks) {
      float4 v0 = r[ks * 2], v1 = r[ks * 2 + 1];
      bf16x8 w;
      w[0] = (short)f2bf(fmaxf(v0.x * gr_[ks * 8 + 0] + br_[ks * 8 + 0], 0.f));
      w[1] = (short)f2bf(fmaxf(v0.y * gr_[ks * 8 + 1] + br_[ks * 8 + 1], 0.f));
      w[2] = (short)f2bf(fmaxf(v0.z * gr_[ks * 8 + 2] + br_[ks * 8 + 2], 0.f));
      w[3] = (short)f2bf(fmaxf(v0.w * gr_[ks * 8 + 3] + br_[ks * 8 + 3], 0.f));
      w[4] = (short)f2bf(fmaxf(v1.x * gr_[ks * 8 + 4] + br_[ks * 8 + 4], 0.f));
      w[5] = (short)f2bf(fmaxf(v1.y * gr_[ks * 8 + 5] + br_[ks * 8 + 5], 0.f));
      w[6] = (short)f2bf(fmaxf(v1.z * gr_[ks * 8 + 6] + br_[ks * 8 + 6], 0.f));
      w[7] = (short)f2bf(fmaxf(v1.w * gr_[ks * 8 + 7] + br_[ks * 8 + 7], 0.f));
      aa[ks] = w;
    }
  } else {
    bf16x8 zf = {0, 0, 0, 0, 0, 0, 0, 0};
    aa[0] = zf; aa[1] = zf;
  }
}

template <int KS>
__device__ __forceinline__ void mfma_step(const u16* __restrict__ bw, const bf16x8* a,
                                          f32x4& acc0, f32x4& acc1, f32x4& acc2, f32x4& acc3) {
#pragma unroll
  for (int ks = 0; ks < KS; ++ks) {
    const u16* bwk = bw + ks * 2048;
    acc0 = __builtin_amdgcn_mfma_f32_16x16x32_bf16(a[ks], *(const bf16x8*)(bwk), acc0, 0, 0, 0);
    acc1 = __builtin_amdgcn_mfma_f32_16x16x32_bf16(a[ks], *(const bf16x8*)(bwk + 512), acc1, 0, 0, 0);
    acc2 = __builtin_amdgcn_mfma_f32_16x16x32_bf16(a[ks], *(const bf16x8*)(bwk + 1024), acc2, 0, 0, 0);
    acc3 = __builtin_amdgcn_mfma_f32_16x16x32_bf16(a[ks], *(const bf16x8*)(bwk + 1536), acc3, 0, 0, 0);
  }
}

__device__ __forceinline__ void store_stats64(int base, int cnt, int am, int kr,
                                              const f32x4& acc0, const f32x4& acc1,
                                              const f32x4& acc2, const f32x4& acc3,
                                              float* __restrict__ out,
                                              float* __restrict__ lsum, float* __restrict__ lss) {
  float s0 = 0.f, s1 = 0.f, s2 = 0.f, s3 = 0.f;
  float q0 = 0.f, q1 = 0.f, q2 = 0.f, q3 = 0.f;
#pragma unroll
  for (int r = 0; r < 4; ++r) {
    int po = base + kr * 4 + r;
    if (po < cnt) {
      float* op = out + (size_t)po * 64 + am;
      op[0] = acc0[r]; op[16] = acc1[r]; op[32] = acc2[r]; op[48] = acc3[r];
      s0 += acc0[r]; q0 += acc0[r] * acc0[r];
      s1 += acc1[r]; q1 += acc1[r] * acc1[r];
      s2 += acc2[r]; q2 += acc2[r] * acc2[r];
      s3 += acc3[r]; q3 += acc3[r] * acc3[r];
    }
  }
  atomicAdd(&lsum[am], s0); atomicAdd(&lss[am], q0);
  atomicAdd(&lsum[am + 16], s1); atomicAdd(&lss[am + 16], q1);
  atomicAdd(&lsum[am + 32], s2); atomicAdd(&lss[am + 32], q2);
  atomicAdd(&lsum[am + 48], s3); atomicAdd(&lss[am + 48], q3);
}

__device__ __forceinline__ void flush_stats(int t, int bid, float* __restrict__ statsOut,
                                            const float* __restrict__ lsum,
                                            const float* __restrict__ lss) {
  if (t < 64) {
    float s = lsum[t], q = lss[t];
    if (s != 0.f || q != 0.f) {
      float* dst = statsOut + (bid & 3) * 128;
      atomicAdd(&dst[t], s);
      atomicAdd(&dst[64 + t], q);
    }
  }
}

// ================= kernels =================

// boot: -1 fill (idx1+claim2) + ctrl + stats + cvt + repacks + TAGGED idx0 scatter
__global__ void k_boot(P p) {
  long tt = (long)blockIdx.x * 256 + threadIdx.x;
  if (tt < p.nfill16) {
    uint4 v;
    v.x = 0xFFFFFFFFu; v.y = 0xFFFFFFFFu; v.z = 0xFFFFFFFFu; v.w = 0xFFFFFFFFu;
    p.fillp[tt] = v;
    return;
  }
  tt -= p.nfill16;
  if (tt < 2560) { p.stats[tt] = 0.f; return; }
  tt -= 2560;
  if (tt < 3) { p.ctrl[tt] = (tt == 0) ? p.N : 0; return; }
  tt -= 3;
  if (tt >= p.prepTotal) return;
  long NC = (long)p.N * 128;
  if (tt < NC) { p.fb[tt] = f2bf(p.feats[tt]); return; }
  tt -= NC;
  if (tt < 221184) { repack1(p.w0, p.wf0, 128, (int)tt); return; }
  tt -= 221184;
  if (tt < 110592) { repack1(p.w1a, p.wf1a, 64, (int)tt); return; }
  tt -= 110592;
  if (tt < 110592) { repack1(p.w1b, p.wf1b, 64, (int)tt); return; }
  tt -= 110592;
  if (tt < 12288) { repack1(p.wz1, p.wfz1, 64, (int)tt); return; }
  tt -= 12288;
  if (tt < 12288) { repack1(p.wz2, p.wfz2, 64, (int)tt); return; }
  tt -= 12288;
  if (tt < p.N) {
    int i = (int)tt;
    int b = p.coors[i * 4], z = p.coors[i * 4 + 1], y = p.coors[i * 4 + 2], x = p.coors[i * 4 + 3];
    p.idx0[((size_t)(b * D0_ + z) * H_ + y) * W_ + x] = 0x55000000 | i;
  }
}

// conv0: 4 groups/block, wave-per-group, chunked 4-deep gather prefetch
__global__ __launch_bounds__(256) void k_conv0(P p) {
  __shared__ int4 scoords[64];
  __shared__ int snbr[1728];
  __shared__ u32 smask[4];
  __shared__ float lsum[64], lss[64];
  const int t = threadIdx.x;
  const int cnt = p.N;
  const int blockBase = blockIdx.x * 64;
  if (blockBase >= cnt) return;
  const int lane = t & 63, wg = t >> 6, am = lane & 15, kr = lane >> 4;
  if (t < 64) {
    lsum[t] = 0.f; lss[t] = 0.f;
    int i = blockBase + t;
    int4 cc = {0, -10000, 0, 0};
    if (i < cnt) cc = *(const int4*)(p.coors + (size_t)i * 4);
    scoords[t] = cc;
  }
  if (t < 4) smask[t] = 0;
  __syncthreads();
  for (int r = t; r < 1728; r += 256) {
    int g = r / 432;
    int rr = r - g * 432;
    int o = rr >> 4;
    int4 cc = scoords[g * 16 + (rr & 15)];
    int nz = cc.y + o / 9 - 1, ny = cc.z + (o / 3) % 3 - 1, nx = cc.w + o % 3 - 1;
    int j = -1;
    if ((u32)nz < (u32)D0_ && (u32)ny < (u32)H_ && (u32)nx < (u32)W_)
      j = detag0(p.idx0[((size_t)(cc.x * D0_ + nz) * H_ + ny) * W_ + nx]);
    snbr[r] = j;
    if (j >= 0) atomicOr(&smask[g], 1u << o);
  }
  __syncthreads();
  int base = blockBase + wg * 16;
  f32x4 acc0 = {0.f, 0.f, 0.f, 0.f};
  f32x4 acc1 = acc0, acc2 = acc0, acc3 = acc0;
  if (base < cnt) {
    u32 mask = smask[wg];
    const int* nb = snbr + wg * 432 + am;
    bf16x8 zf = {0, 0, 0, 0, 0, 0, 0, 0};
    while (mask) {
      int os0 = __builtin_ctz(mask); mask &= mask - 1;
      int os1 = -1, os2 = -1, os3 = -1;
      if (mask) { os1 = __builtin_ctz(mask); mask &= mask - 1; }
      if (mask) { os2 = __builtin_ctz(mask); mask &= mask - 1; }
      if (mask) { os3 = __builtin_ctz(mask); mask &= mask - 1; }
      int j0 = nb[os0 * 16];
      int j1 = (os1 >= 0) ? nb[os1 * 16] : -1;
      int j2 = (os2 >= 0) ? nb[os2 * 16] : -1;
      int j3 = (os3 >= 0) ? nb[os3 * 16] : -1;
      bf16x8 a0[4], a1[4], a2[4], a3[4];
#pragma unroll
      for (int ks = 0; ks < 4; ++ks) {
        a0[ks] = (j0 >= 0) ? *(const bf16x8*)(p.fb + (size_t)j0 * 128 + ks * 32 + kr * 8) : zf;
        a1[ks] = (j1 >= 0) ? *(const bf16x8*)(p.fb + (size_t)j1 * 128 + ks * 32 + kr * 8) : zf;
        a2[ks] = (j2 >= 0) ? *(const bf16x8*)(p.fb + (size_t)j2 * 128 + ks * 32 + kr * 8) : zf;
        a3[ks] = (j3 >= 0) ? *(const bf16x8*)(p.fb + (size_t)j3 * 128 + ks * 32 + kr * 8) : zf;
      }
      mfma_step<4>(p.wf0 + (size_t)os0 * 8192 + lane * 8, a0, acc0, acc1, acc2, acc3);
      if (os1 >= 0) mfma_step<4>(p.wf0 + (size_t)os1 * 8192 + lane * 8, a1, acc0, acc1, acc2, acc3);
      if (os2 >= 0) mfma_step<4>(p.wf0 + (size_t)os2 * 8192 + lane * 8, a2, acc0, acc1, acc2, acc3);
      if (os3 >= 0) mfma_step<4>(p.wf0 + (size_t)os3 * 8192 + lane * 8, a3, acc0, acc1, acc2, acc3);
    }
    store_stats64(base, cnt, am, kr, acc0, acc1, acc2, acc3, p.xb0, lsum, lss);
  }
  __syncthreads();
  if (t < 64) {
    flush_stats(t, blockIdx.x, p.stats + 0, lsum, lss);
    claim_ep(t, blockBase, cnt, p.coors, p.idx0, D0_, D1_, p.idx1, p.coords1, p.nbrz1,
             p.ctrl + 1, 1);
  }
}

// convz1: BN0-inline, 3-tap full prefetch + nbr1/gmask1 gen + stats1 + claim2
__global__ __launch_bounds__(256) void k_convz1(P p) {
  const int cnt1 = p.ctrl[1];
  const int blockBase = blockIdx.x * 64;
  if (blockBase >= cnt1) return;
  __shared__ int4 scoords[64];
  __shared__ float lsum[64], lss[64], ggs[64], bbs[64];
  __shared__ u32 smask[4];
  const int t = threadIdx.x;
  const int lane = t & 63, wg = t >> 6, am = lane & 15, kr = lane >> 4;
  if (t < 64) {
    lsum[t] = 0.f; lss[t] = 0.f;
    int i = blockBase + t;
    int4 cc = {0, -10000, 0, 0};
    if (i < cnt1) cc = *(const int4*)(p.coords1 + (size_t)i * 4);
    scoords[t] = cc;
  }
  if (t < 4) smask[t] = 0;
  bn_pre(p.stats + 0, p.N, p.g0, p.b0, ggs, bbs, t);
  __syncthreads();
  for (int r = t; r < 1728; r += 256) {
    int g = r / 432;
    int rr = r - g * 432;
    int o = rr >> 4;
    int4 cc = scoords[g * 16 + (rr & 15)];
    int nz = cc.y + o / 9 - 1, ny = cc.z + (o / 3) % 3 - 1, nx = cc.w + o % 3 - 1;
    int j = -1;
    if ((u32)nz < (u32)D1_ && (u32)ny < (u32)H_ && (u32)nx < (u32)W_)
      j = p.idx1[((size_t)(cc.x * D1_ + nz) * H_ + ny) * W_ + nx];
    p.nbr1[(size_t)(blockIdx.x * 4 + g) * 432 + rr] = j;
    if (j >= 0) atomicOr(&smask[g], 1u << o);
  }
  __syncthreads();
  if (t < 4) p.gmask1[blockIdx.x * 4 + t] = smask[t];
  float gr_[16], br_[16];
#pragma unroll
  for (int ks = 0; ks < 2; ++ks)
#pragma unroll
    for (int e = 0; e < 8; ++e) {
      int c = ks * 32 + kr * 8 + e;
      gr_[ks * 8 + e] = ggs[c];
      br_[ks * 8 + e] = bbs[c];
    }
  int base = blockBase + wg * 16;
  f32x4 acc0 = {0.f, 0.f, 0.f, 0.f};
  f32x4 acc1 = acc0, acc2 = acc0, acc3 = acc0;
  if (base < cnt1) {
    int pt = base + am;
    bool vpt = pt < cnt1;
    const int* np = p.nbrz1 + (size_t)pt * 3;
    int j0 = vpt ? np[0] : -1;
    int j1 = vpt ? np[1] : -1;
    int j2 = vpt ? np[2] : -1;
    float4 r0[4], r1[4], r2[4];
    loadRaw64(p.xb0, j0, kr, r0);
    loadRaw64(p.xb0, j1, kr, r1);
    loadRaw64(p.xb0, j2, kr, r2);
    bf16x8 a[2];
    cvtA64(r0, j0, gr_, br_, a);
    mfma_step<2>(p.wfz1 + lane * 8, a, acc0, acc1, acc2, acc3);
    cvtA64(r1, j1, gr_, br_, a);
    mfma_step<2>(p.wfz1 + 4096 + lane * 8, a, acc0, acc1, acc2, acc3);
    cvtA64(r2, j2, gr_, br_, a);
    mfma_step<2>(p.wfz1 + 8192 + lane * 8, a, acc0, acc1, acc2, acc3);
    store_stats64(base, cnt1, am, kr, acc0, acc1, acc2, acc3, p.xb1, lsum, lss);
  }
  __syncthreads();
  if (t < 64) {
    flush_stats(t, blockIdx.x, p.stats + 512, lsum, lss);
    claim_ep(t, blockBase, cnt1, p.coords1, p.idx1, D1_, D2_, p.claim2, p.coords2, p.nbrz2,
             p.ctrl + 2, 0);
  }
}

// conv1 (a/b): 4 groups/block, wave-per-group, chunked 4-deep raw prefetch + inline BN
__global__ __launch_bounds__(256) void k_conv1(P p, const float* __restrict__ xin,
                                               float* __restrict__ xout,
                                               const u16* __restrict__ wf,
                                               const float* __restrict__ sIn,
                                               float* __restrict__ sOut,
                                               const float* __restrict__ gam,
                                               const float* __restrict__ bet) {
  const int cnt1 = p.ctrl[1];
  const int blockBase = blockIdx.x * 64;
  if (blockBase >= cnt1) return;
  __shared__ float lsum[64], lss[64], ggs[64], bbs[64];
  const int t = threadIdx.x;
  const int lane = t & 63, wg = t >> 6, am = lane & 15, kr = lane >> 4;
  if (t < 64) { lsum[t] = 0.f; lss[t] = 0.f; }
  bn_pre(sIn, cnt1, gam, bet, ggs, bbs, t);
  __syncthreads();
  float gr_[16], br_[16];
#pragma unroll
  for (int ks = 0; ks < 2; ++ks)
#pragma unroll
    for (int e = 0; e < 8; ++e) {
      int c = ks * 32 + kr * 8 + e;
      gr_[ks * 8 + e] = ggs[c];
      br_[ks * 8 + e] = bbs[c];
    }
  int base = blockBase + wg * 16;
  f32x4 acc0 = {0.f, 0.f, 0.f, 0.f};
  f32x4 acc1 = acc0, acc2 = acc0, acc3 = acc0;
  if (base < cnt1) {
    int g = blockIdx.x * 4 + wg;
    u32 mask = p.gmask1[g];
    const int* nb = p.nbr1 + (size_t)g * 432 + am;
    bf16x8 a[2];
    while (mask) {
      int os0 = __builtin_ctz(mask); mask &= mask - 1;
      int os1 = -1, os2 = -1, os3 = -1;
      if (mask) { os1 = __builtin_ctz(mask); mask &= mask - 1; }
      if (mask) { os2 = __builtin_ctz(mask); mask &= mask - 1; }
      if (mask) { os3 = __builtin_ctz(mask); mask &= mask - 1; }
      int j0 = nb[os0 * 16];
      int j1 = (os1 >= 0) ? nb[os1 * 16] : -1;
      int j2 = (os2 >= 0) ? nb[os2 * 16] : -1;
      int j3 = (os3 >= 0) ? nb[os3 * 16] : -1;
      float4 r0[4], r1[4], r2[4], r3[4];
      loadRaw64(xin, j0, kr, r0);
      loadRaw64(xin, j1, kr, r1);
      loadRaw64(xin, j2, kr, r2);
      loadRaw64(xin, j3, kr, r3);
      cvtA64(r0, j0, gr_, br_, a);
      mfma_step<2>(wf + (size_t)os0 * 4096 + lane * 8, a, acc0, acc1, acc2, acc3);
      if (os1 >= 0) {
        cvtA64(r1, j1, gr_, br_, a);
        mfma_step<2>(wf + (size_t)os1 * 4096 + lane * 8, a, acc0, acc1, acc2, acc3);
      }
      if (os2 >= 0) {
        cvtA64(r2, j2, gr_, br_, a);
        mfma_step<2>(wf + (size_t)os2 * 4096 + lane * 8, a, acc0, acc1, acc2, acc3);
      }
      if (os3 >= 0) {
        cvtA64(r3, j3, gr_, br_, a);
        mfma_step<2>(wf + (size_t)os3 * 4096 + lane * 8, a, acc0, acc1, acc2, acc3);
      }
    }
    store_stats64(base, cnt1, am, kr, acc0, acc1, acc2, acc3, xout, lsum, lss);
  }
  __syncthreads();
  flush_stats(t, blockIdx.x, sOut, lsum, lss);
}

// convz2: BN3-inline, 3-tap full prefetch + stats4
__global__ __launch_bounds__(256) void k_convz2(P p) {
  const int cnt1 = p.ctrl[1];
  const int cnt2 = p.ctrl[2];
  const int blockBase = blockIdx.x * 64;
  if (blockBase >= cnt2) return;
  __shared__ float lsum[64], lss[64], ggs[64], bbs[64];
  const int t = threadIdx.x;
  const int lane = t & 63, wg = t >> 6, am = lane & 15, kr = lane >> 4;
  if (t < 64) { lsum[t] = 0.f; lss[t] = 0.f; }
  bn_pre(p.stats + 1536, cnt1, p.g3, p.b3, ggs, bbs, t);
  __syncthreads();
  float gr_[16], br_[16];
#pragma unroll
  for (int ks = 0; ks < 2; ++ks)
#pragma unroll
    for (int e = 0; e < 8; ++e) {
      int c = ks * 32 + kr * 8 + e;
      gr_[ks * 8 + e] = ggs[c];
      br_[ks * 8 + e] = bbs[c];
    }
  int base = blockBase + wg * 16;
  if (base < cnt2) {
    int pt = base + am;
    bool vpt = pt < cnt2;
    const int* np = p.nbrz2 + (size_t)pt * 3;
    int j0 = vpt ? np[0] : -1;
    int j1 = vpt ? np[1] : -1;
    int j2 = vpt ? np[2] : -1;
    float4 r0[4], r1[4], r2[4];
    loadRaw64(p.xb3, j0, kr, r0);
    loadRaw64(p.xb3, j1, kr, r1);
    loadRaw64(p.xb3, j2, kr, r2);
    f32x4 acc0 = {0.f, 0.f, 0.f, 0.f};
    f32x4 acc1 = acc0, acc2 = acc0, acc3 = acc0;
    bf16x8 a[2];
    cvtA64(r0, j0, gr_, br_, a);
    mfma_step<2>(p.wfz2 + lane * 8, a, acc0, acc1, acc2, acc3);
    cvtA64(r1, j1, gr_, br_, a);
    mfma_step<2>(p.wfz2 + 4096 + lane * 8, a, acc0, acc1, acc2, acc3);
    cvtA64(r2, j2, gr_, br_, a);
    mfma_step<2>(p.wfz2 + 8192 + lane * 8, a, acc0, acc1, acc2, acc3);
    store_stats64(base, cnt2, am, kr, acc0, acc1, acc2, acc3, p.xb4, lsum, lss);
  }
  __syncthreads();
  flush_stats(t, blockIdx.x, p.stats + 2048, lsum, lss);
}

// dense output
__global__ void k_s7(P p) {
  const int XQ = W_ / 4;
  const int cnt2 = p.ctrl[2];
  const long total = (long)B_ * 64 * D2_ * H_ * XQ;
  long tt = (long)blockIdx.x * 256 + threadIdx.x;
  if (tt >= total) return;
  const float* st = p.stats + 2048;
  int xq = (int)(tt % XQ);
  long row = tt / XQ;
  int y = (int)(row % H_);
  long r2 = row / H_;
  int oz = (int)(r2 % D2_);
  r2 /= D2_;
  int c = (int)(r2 & 63);
  int b = (int)(r2 >> 6);
  float s = 0.f, q = 0.f;
#pragma unroll
  for (int k = 0; k < 4; ++k) { s += st[k * 128 + c]; q += st[k * 128 + 64 + c]; }
  float cf = (float)(cnt2 > 0 ? cnt2 : 1);
  float mean = s / cf;
  float var = q / cf - mean * mean;
  float inv = rsqrtf(var + 1e-3f);
  float g = p.g4[c] * inv;
  float bb = p.b4[c] - mean * g;
  int pos = ((b * D2_ + oz) * H_ + y) * W_ + xq * 4;
  int4 ids = *(const int4*)(p.claim2 + pos);
  float4 v;
  v.x = (ids.x >= 0) ? fmaxf(p.xb4[(size_t)ids.x * 64 + c] * g + bb, 0.f) : 0.f;
  v.y = (ids.y >= 0) ? fmaxf(p.xb4[(size_t)ids.y * 64 + c] * g + bb, 0.f) : 0.f;
  v.z = (ids.z >= 0) ? fmaxf(p.xb4[(size_t)ids.z * 64 + c] * g + bb, 0.f) : 0.f;
  v.w = (ids.w >= 0) ? fmaxf(p.xb4[(size_t)ids.w * 64 + c] * g + bb, 0.f) : 0.f;
  *(float4*)(p.out + (size_t)row * W_ + xq * 4) = v;
}

extern "C" void kernel_launch(void* const* d_in, const int* in_sizes, int n_in,
                              void* d_out, int out_size, void* d_ws, size_t ws_size,
                              hipStream_t stream) {
  const int N = in_sizes[0] / 128;
  const int cap1 = 2 * N + 8;
  const int cap2 = 4 * N + 8;
  const int ng1 = (cap1 + 15) / 16;

  char* ws = (char*)d_ws;
  size_t off = 0;
  auto alloc = [&](size_t bytes) -> void* {
    size_t o = off;
    off = (off + bytes + 255) & ~(size_t)255;
    return (void*)(ws + o);
  };

  P p;
  p.ctrl = (int*)alloc(16);
  p.stats = (float*)alloc(2560 * 4);
  p.idx0 = (int*)alloc((size_t)B_ * D0_ * HW_ * 4);   // tagged; no pre-fill needed
  size_t fill_beg = off;
  p.idx1 = (int*)alloc((size_t)B_ * D1_ * HW_ * 4);
  p.claim2 = (int*)alloc((size_t)B_ * D2_ * HW_ * 4);
  size_t fill_end = off;
  p.nbr1 = (int*)alloc((size_t)(ng1 + 4) * 432 * 4);
  p.gmask1 = (u32*)alloc((size_t)(ng1 + 4) * 4);
  p.nbrz1 = (int*)alloc((size_t)cap1 * 3 * 4);
  p.nbrz2 = (int*)alloc((size_t)cap2 * 3 * 4);
  p.coords1 = (int*)alloc((size_t)cap1 * 4 * 4);
  p.coords2 = (int*)alloc((size_t)cap2 * 4 * 4);
  p.xb0 = (float*)alloc((size_t)N * 64 * 4);
  p.xb1 = (float*)alloc((size_t)cap1 * 64 * 4);
  p.xb2 = (float*)alloc((size_t)cap1 * 64 * 4);
  p.xb3 = (float*)alloc((size_t)cap1 * 64 * 4);
  p.xb4 = (float*)alloc((size_t)cap2 * 64 * 4);
  p.fb = (u16*)alloc((size_t)N * 128 * 2);
  p.wf0 = (u16*)alloc((size_t)27 * 4 * 2048 * 2);
  p.wf1a = (u16*)alloc((size_t)27 * 2 * 2048 * 2);
  p.wf1b = (u16*)alloc((size_t)27 * 2 * 2048 * 2);
  p.wfz1 = (u16*)alloc((size_t)3 * 2 * 2048 * 2);
  p.wfz2 = (u16*)alloc((size_t)3 * 2 * 2048 * 2);

  p.feats = (const float*)d_in[0];
  p.coors = (const int*)d_in[1];
  p.w0 = (const float*)d_in[3];
  p.g0 = (const float*)d_in[4]; p.b0 = (const float*)d_in[5];
  p.wz1 = (const float*)d_in[6];
  p.g1 = (const float*)d_in[7]; p.b1 = (const float*)d_in[8];
  p.w1a = (const float*)d_in[9];
  p.g2 = (const float*)d_in[10]; p.b2 = (const float*)d_in[11];
  p.w1b = (const float*)d_in[12];
  p.g3 = (const float*)d_in[13]; p.b3 = (const float*)d_in[14];
  p.wz2 = (const float*)d_in[15];
  p.g4 = (const float*)d_in[16]; p.b4 = (const float*)d_in[17];
  p.out = (float*)d_out;
  p.fillp = (uint4*)(ws + fill_beg);
  p.N = N;
  p.nfill16 = (int)((fill_end - fill_beg) / 16);
  p.prepTotal = (long)N * 128 + 221184 + 110592 + 110592 + 12288 + 12288 + N;

  const int nb0 = (N + 63) / 64;
  const int nb1 = (cap1 + 63) / 64;
  const int nb2 = (cap2 + 63) / 64;
  const long outThreads = (long)B_ * 64 * D2_ * H_ * (W_ / 4);
  const long bootTotal = (long)p.nfill16 + 2563 + p.prepTotal;

  k_boot<<<dim3((unsigned)((bootTotal + 255) / 256)), 256, 0, stream>>>(p);
  k_conv0<<<dim3(nb0), 256, 0, stream>>>(p);
  k_convz1<<<dim3(nb1), 256, 0, stream>>>(p);
  k_conv1<<<dim3(nb1), 256, 0, stream>>>(p, p.xb1, p.xb2, p.wf1a, p.stats + 512,
                                         p.stats + 1024, p.g1, p.b1);
  k_conv1<<<dim3(nb1), 256, 0, stream>>>(p, p.xb2, p.xb3, p.wf1b, p.stats + 1024,
                                         p.stats + 1536, p.g2, p.b2);
  k_convz2<<<dim3(nb2), 256, 0, stream>>>(p);
  k_s7<<<dim3((unsigned)((outThreads + 255) / 256)), 256, 0, stream>>>(p);
}

// Round 13
// 360.796 us; speedup vs baseline: 1.0430x; 1.0430x over previous
//
#include <hip/hip_runtime.h>

typedef unsigned short u16;
typedef unsigned int u32;
typedef unsigned long long u64;
typedef __attribute__((ext_vector_type(8))) short bf16x8;
typedef __attribute__((ext_vector_type(4))) float f32x4;

#define H_ 200
#define W_ 176
#define HW_ (200 * 176)
#define D0_ 41
#define D1_ 20
#define D2_ 9
#define B_ 2

__device__ __forceinline__ u16 f2bf(float f) {
  union { float f; u32 u; } c; c.f = f;
  u32 u = c.u;
  u32 r = (u + 0x7fffu + ((u >> 16) & 1u)) >> 16;
  return (u16)r;
}
__device__ __forceinline__ float bf2f(u16 v) {
  union { u32 u; float f; } c; c.u = ((u32)v) << 16; return c.f;
}

// idx0 entries are tagged: 0x55000000 | point_index; anything else decodes -1.
__device__ __forceinline__ int detag0(int v) {
  return (((u32)v >> 24) == 0x55u) ? (v & 0xFFFFFF) : -1;
}

struct P {
  const float* feats; const int* coors;
  const float *w0, *w1a, *w1b, *wz1, *wz2;
  const float *g0, *b0, *g1, *b1, *g2, *b2, *g3, *b3, *g4, *b4;
  int* ctrl; float* stats;
  int *idx0, *idx1, *claim2;
  int* nbr1; u32* gmask1;
  int *nbrz1, *nbrz2, *coords1, *coords2;
  u16 *xb0, *xb1, *xb2, *xb3, *xb4;   // bf16 raw (pre-BN) intermediate features
  u16 *fb, *wf0, *wf1a, *wf1b, *wfz1, *wfz2;
  float* out;
  uint4* fillp;
  int N, nfill16;
  long prepTotal;
};

// ---- weight repack: (NOFF,K,64) fp32 -> bf16 fragment order [o][ks][nt][lane][8] ----
__device__ __forceinline__ void repack1(const float* __restrict__ w, u16* __restrict__ frag,
                                        int K, int t) {
  int j = t & 7;
  int lane = (t >> 3) & 63;
  int nt = (t >> 9) & 3;
  int rest = t >> 11;
  int KS = K / 32;
  int ks = rest % KS;
  int o = rest / KS;
  int k = ks * 32 + (lane >> 4) * 8 + j;
  int n = nt * 16 + (lane & 15);
  frag[t] = f2bf(w[((size_t)o * K + k) * 64 + n]);
}

// ---- wave claim (wave 0 only) ----
__device__ __forceinline__ void claim_ep(int t, int base, int cnt,
                                         const int* __restrict__ coordsIn,
                                         const int* __restrict__ idxin, int Din, int Dout,
                                         int* __restrict__ claim, int* __restrict__ coords_out,
                                         int* __restrict__ nbrzN, int* __restrict__ outcnt,
                                         int tagged) {
  int i = base + t;
  bool w0 = false, w1 = false;
  int pos0 = 0, pos1 = 0, oz0 = -1, oz1 = -1;
  int b = 0, z = 0, yy = 0, xx = 0;
  if (i < cnt) {
    int4 cc = *(const int4*)(coordsIn + (size_t)i * 4);
    b = cc.x; z = cc.y; yy = cc.z; xx = cc.w;
    if (z & 1) {
      int oz = (z - 1) >> 1;
      if (oz < Dout) oz0 = oz;
    } else {
      int oz = z >> 1;
      if (oz < Dout) oz0 = oz;
      if (z >= 2) oz1 = oz - 1;
    }
    if (oz0 >= 0) {
      pos0 = ((b * Dout + oz0) * H_ + yy) * W_ + xx;
      w0 = (atomicCAS(&claim[pos0], -1, -2) == -1);
    }
    if (oz1 >= 0) {
      pos1 = ((b * Dout + oz1) * H_ + yy) * W_ + xx;
      w1 = (atomicCAS(&claim[pos1], -1, -2) == -1);
    }
  }
  u64 m0 = __ballot(w0), m1 = __ballot(w1);
  int c0 = __popcll(m0), c1 = __popcll(m1);
  int lane = t & 63;
  u64 lt = (lane == 63) ? 0x7FFFFFFFFFFFFFFFull : ((1ull << lane) - 1ull);
  int bse2 = 0;
  if (lane == 0 && (c0 + c1) > 0) bse2 = atomicAdd(outcnt, c0 + c1);
  bse2 = __shfl(bse2, 0);
  if (w0) {
    int id = bse2 + __popcll(m0 & lt);
    claim[pos0] = id;
    coords_out[id * 4 + 0] = b; coords_out[id * 4 + 1] = oz0;
    coords_out[id * 4 + 2] = yy; coords_out[id * 4 + 3] = xx;
    size_t bse = ((size_t)(b * Din + 2 * oz0) * H_ + yy) * W_ + xx;
    int v0 = idxin[bse], v1 = idxin[bse + HW_], v2 = idxin[bse + 2 * (size_t)HW_];
    nbrzN[id * 3 + 0] = tagged ? detag0(v0) : v0;
    nbrzN[id * 3 + 1] = tagged ? detag0(v1) : v1;
    nbrzN[id * 3 + 2] = tagged ? detag0(v2) : v2;
  }
  if (w1) {
    int id = bse2 + c0 + __popcll(m1 & lt);
    claim[pos1] = id;
    coords_out[id * 4 + 0] = b; coords_out[id * 4 + 1] = oz1;
    coords_out[id * 4 + 2] = yy; coords_out[id * 4 + 3] = xx;
    size_t bse = ((size_t)(b * Din + 2 * oz1) * H_ + yy) * W_ + xx;
    int v0 = idxin[bse], v1 = idxin[bse + HW_], v2 = idxin[bse + 2 * (size_t)HW_];
    nbrzN[id * 3 + 0] = tagged ? detag0(v0) : v0;
    nbrzN[id * 3 + 1] = tagged ? detag0(v1) : v1;
    nbrzN[id * 3 + 2] = tagged ? detag0(v2) : v2;
  }
}

__device__ __forceinline__ void bn_pre(const float* __restrict__ statsIn, int cntN,
                                       const float* __restrict__ gamma,
                                       const float* __restrict__ beta,
                                       float* __restrict__ ggs, float* __restrict__ bbs, int t) {
  if (t < 64) {
    float s = 0.f, q = 0.f;
#pragma unroll
    for (int k = 0; k < 4; ++k) { s += statsIn[k * 128 + t]; q += statsIn[k * 128 + 64 + t]; }
    float cf = (float)(cntN > 0 ? cntN : 1);
    float mean = s / cf;
    float var = q / cf - mean * mean;
    float inv = rsqrtf(var + 1e-3f);
    float g = gamma[t] * inv;
    ggs[t] = g;
    bbs[t] = beta[t] - mean * g;
  }
}

// raw bf16 K=64 feature row load (2 x 16B); skipped when j < 0
__device__ __forceinline__ void loadRawB16(const u16* __restrict__ xp, int j, int kr,
                                           bf16x8* __restrict__ r) {
  if (j >= 0) {
    const u16* src = xp + (size_t)j * 64 + kr * 8;
    r[0] = *(const bf16x8*)(src);
    r[1] = *(const bf16x8*)(src + 32);
  }
}

// BN+ReLU convert raw bf16 -> bf16 A-fragments; zero when j < 0
__device__ __forceinline__ void cvtB16(const bf16x8* __restrict__ r, int j,
                                       const float* gr_, const float* br_, bf16x8* aa) {
  if (j >= 0) {
#pragma unroll
    for (int ks = 0; ks < 2; ++ks) {
      bf16x8 w;
#pragma unroll
      for (int e = 0; e < 8; ++e) {
        float v = bf2f((u16)r[ks][e]);
        w[e] = (short)f2bf(fmaxf(v * gr_[ks * 8 + e] + br_[ks * 8 + e], 0.f));
      }
      aa[ks] = w;
    }
  } else {
    bf16x8 zf = {0, 0, 0, 0, 0, 0, 0, 0};
    aa[0] = zf; aa[1] = zf;
  }
}

template <int KS>
__device__ __forceinline__ void mfma_step(const u16* __restrict__ bw, const bf16x8* a,
                                          f32x4& acc0, f32x4& acc1, f32x4& acc2, f32x4& acc3) {
#pragma unroll
  for (int ks = 0; ks < KS; ++ks) {
    const u16* bwk = bw + ks * 2048;
    acc0 = __builtin_amdgcn_mfma_f32_16x16x32_bf16(a[ks], *(const bf16x8*)(bwk), acc0, 0, 0, 0);
    acc1 = __builtin_amdgcn_mfma_f32_16x16x32_bf16(a[ks], *(const bf16x8*)(bwk + 512), acc1, 0, 0, 0);
    acc2 = __builtin_amdgcn_mfma_f32_16x16x32_bf16(a[ks], *(const bf16x8*)(bwk + 1024), acc2, 0, 0, 0);
    acc3 = __builtin_amdgcn_mfma_f32_16x16x32_bf16(a[ks], *(const bf16x8*)(bwk + 1536), acc3, 0, 0, 0);
  }
}

// epilogue: bf16 feature store + fp32 stats accumulate (stats from fp32 accs)
__device__ __forceinline__ void store_stats64(int base, int cnt, int am, int kr,
                                              const f32x4& acc0, const f32x4& acc1,
                                              const f32x4& acc2, const f32x4& acc3,
                                              u16* __restrict__ out,
                                              float* __restrict__ lsum, float* __restrict__ lss) {
  float s0 = 0.f, s1 = 0.f, s2 = 0.f, s3 = 0.f;
  float q0 = 0.f, q1 = 0.f, q2 = 0.f, q3 = 0.f;
#pragma unroll
  for (int r = 0; r < 4; ++r) {
    int po = base + kr * 4 + r;
    if (po < cnt) {
      u16* op = out + (size_t)po * 64 + am;
      op[0] = f2bf(acc0[r]); op[16] = f2bf(acc1[r]);
      op[32] = f2bf(acc2[r]); op[48] = f2bf(acc3[r]);
      s0 += acc0[r]; q0 += acc0[r] * acc0[r];
      s1 += acc1[r]; q1 += acc1[r] * acc1[r];
      s2 += acc2[r]; q2 += acc2[r] * acc2[r];
      s3 += acc3[r]; q3 += acc3[r] * acc3[r];
    }
  }
  atomicAdd(&lsum[am], s0); atomicAdd(&lss[am], q0);
  atomicAdd(&lsum[am + 16], s1); atomicAdd(&lss[am + 16], q1);
  atomicAdd(&lsum[am + 32], s2); atomicAdd(&lss[am + 32], q2);
  atomicAdd(&lsum[am + 48], s3); atomicAdd(&lss[am + 48], q3);
}

__device__ __forceinline__ void flush_stats(int t, int bid, float* __restrict__ statsOut,
                                            const float* __restrict__ lsum,
                                            const float* __restrict__ lss) {
  if (t < 64) {
    float s = lsum[t], q = lss[t];
    if (s != 0.f || q != 0.f) {
      float* dst = statsOut + (bid & 3) * 128;
      atomicAdd(&dst[t], s);
      atomicAdd(&dst[64 + t], q);
    }
  }
}

// ================= kernels =================

// boot: -1 fill (idx1+claim2) + ctrl + stats + cvt + repacks + TAGGED idx0 scatter
__global__ void k_boot(P p) {
  long tt = (long)blockIdx.x * 256 + threadIdx.x;
  if (tt < p.nfill16) {
    uint4 v;
    v.x = 0xFFFFFFFFu; v.y = 0xFFFFFFFFu; v.z = 0xFFFFFFFFu; v.w = 0xFFFFFFFFu;
    p.fillp[tt] = v;
    return;
  }
  tt -= p.nfill16;
  if (tt < 2560) { p.stats[tt] = 0.f; return; }
  tt -= 2560;
  if (tt < 3) { p.ctrl[tt] = (tt == 0) ? p.N : 0; return; }
  tt -= 3;
  if (tt >= p.prepTotal) return;
  long NC = (long)p.N * 128;
  if (tt < NC) { p.fb[tt] = f2bf(p.feats[tt]); return; }
  tt -= NC;
  if (tt < 221184) { repack1(p.w0, p.wf0, 128, (int)tt); return; }
  tt -= 221184;
  if (tt < 110592) { repack1(p.w1a, p.wf1a, 64, (int)tt); return; }
  tt -= 110592;
  if (tt < 110592) { repack1(p.w1b, p.wf1b, 64, (int)tt); return; }
  tt -= 110592;
  if (tt < 12288) { repack1(p.wz1, p.wfz1, 64, (int)tt); return; }
  tt -= 12288;
  if (tt < 12288) { repack1(p.wz2, p.wfz2, 64, (int)tt); return; }
  tt -= 12288;
  if (tt < p.N) {
    int i = (int)tt;
    int b = p.coors[i * 4], z = p.coors[i * 4 + 1], y = p.coors[i * 4 + 2], x = p.coors[i * 4 + 3];
    p.idx0[((size_t)(b * D0_ + z) * H_ + y) * W_ + x] = 0x55000000 | i;
  }
}

// conv0: 4 groups/block, wave-per-group, chunked 4-deep gather prefetch
__global__ __launch_bounds__(256) void k_conv0(P p) {
  __shared__ int4 scoords[64];
  __shared__ int snbr[1728];
  __shared__ u32 smask[4];
  __shared__ float lsum[64], lss[64];
  const int t = threadIdx.x;
  const int cnt = p.N;
  const int blockBase = blockIdx.x * 64;
  if (blockBase >= cnt) return;
  const int lane = t & 63, wg = t >> 6, am = lane & 15, kr = lane >> 4;
  if (t < 64) {
    lsum[t] = 0.f; lss[t] = 0.f;
    int i = blockBase + t;
    int4 cc = {0, -10000, 0, 0};
    if (i < cnt) cc = *(const int4*)(p.coors + (size_t)i * 4);
    scoords[t] = cc;
  }
  if (t < 4) smask[t] = 0;
  __syncthreads();
  for (int r = t; r < 1728; r += 256) {
    int g = r / 432;
    int rr = r - g * 432;
    int o = rr >> 4;
    int4 cc = scoords[g * 16 + (rr & 15)];
    int nz = cc.y + o / 9 - 1, ny = cc.z + (o / 3) % 3 - 1, nx = cc.w + o % 3 - 1;
    int j = -1;
    if ((u32)nz < (u32)D0_ && (u32)ny < (u32)H_ && (u32)nx < (u32)W_)
      j = detag0(p.idx0[((size_t)(cc.x * D0_ + nz) * H_ + ny) * W_ + nx]);
    snbr[r] = j;
    if (j >= 0) atomicOr(&smask[g], 1u << o);
  }
  __syncthreads();
  int base = blockBase + wg * 16;
  f32x4 acc0 = {0.f, 0.f, 0.f, 0.f};
  f32x4 acc1 = acc0, acc2 = acc0, acc3 = acc0;
  if (base < cnt) {
    u32 mask = smask[wg];
    const int* nb = snbr + wg * 432 + am;
    bf16x8 zf = {0, 0, 0, 0, 0, 0, 0, 0};
    while (mask) {
      int os0 = __builtin_ctz(mask); mask &= mask - 1;
      int os1 = -1, os2 = -1, os3 = -1;
      if (mask) { os1 = __builtin_ctz(mask); mask &= mask - 1; }
      if (mask) { os2 = __builtin_ctz(mask); mask &= mask - 1; }
      if (mask) { os3 = __builtin_ctz(mask); mask &= mask - 1; }
      int j0 = nb[os0 * 16];
      int j1 = (os1 >= 0) ? nb[os1 * 16] : -1;
      int j2 = (os2 >= 0) ? nb[os2 * 16] : -1;
      int j3 = (os3 >= 0) ? nb[os3 * 16] : -1;
      bf16x8 a0[4], a1[4], a2[4], a3[4];
#pragma unroll
      for (int ks = 0; ks < 4; ++ks) {
        a0[ks] = (j0 >= 0) ? *(const bf16x8*)(p.fb + (size_t)j0 * 128 + ks * 32 + kr * 8) : zf;
        a1[ks] = (j1 >= 0) ? *(const bf16x8*)(p.fb + (size_t)j1 * 128 + ks * 32 + kr * 8) : zf;
        a2[ks] = (j2 >= 0) ? *(const bf16x8*)(p.fb + (size_t)j2 * 128 + ks * 32 + kr * 8) : zf;
        a3[ks] = (j3 >= 0) ? *(const bf16x8*)(p.fb + (size_t)j3 * 128 + ks * 32 + kr * 8) : zf;
      }
      mfma_step<4>(p.wf0 + (size_t)os0 * 8192 + lane * 8, a0, acc0, acc1, acc2, acc3);
      if (os1 >= 0) mfma_step<4>(p.wf0 + (size_t)os1 * 8192 + lane * 8, a1, acc0, acc1, acc2, acc3);
      if (os2 >= 0) mfma_step<4>(p.wf0 + (size_t)os2 * 8192 + lane * 8, a2, acc0, acc1, acc2, acc3);
      if (os3 >= 0) mfma_step<4>(p.wf0 + (size_t)os3 * 8192 + lane * 8, a3, acc0, acc1, acc2, acc3);
    }
    store_stats64(base, cnt, am, kr, acc0, acc1, acc2, acc3, p.xb0, lsum, lss);
  }
  __syncthreads();
  if (t < 64) {
    flush_stats(t, blockIdx.x, p.stats + 0, lsum, lss);
    claim_ep(t, blockBase, cnt, p.coors, p.idx0, D0_, D1_, p.idx1, p.coords1, p.nbrz1,
             p.ctrl + 1, 1);
  }
}

// convz1: BN0-inline, 3-tap full prefetch + nbr1/gmask1 gen + stats1 + claim2
__global__ __launch_bounds__(256) void k_convz1(P p) {
  const int cnt1 = p.ctrl[1];
  const int blockBase = blockIdx.x * 64;
  if (blockBase >= cnt1) return;
  __shared__ int4 scoords[64];
  __shared__ float lsum[64], lss[64], ggs[64], bbs[64];
  __shared__ u32 smask[4];
  const int t = threadIdx.x;
  const int lane = t & 63, wg = t >> 6, am = lane & 15, kr = lane >> 4;
  if (t < 64) {
    lsum[t] = 0.f; lss[t] = 0.f;
    int i = blockBase + t;
    int4 cc = {0, -10000, 0, 0};
    if (i < cnt1) cc = *(const int4*)(p.coords1 + (size_t)i * 4);
    scoords[t] = cc;
  }
  if (t < 4) smask[t] = 0;
  bn_pre(p.stats + 0, p.N, p.g0, p.b0, ggs, bbs, t);
  __syncthreads();
  for (int r = t; r < 1728; r += 256) {
    int g = r / 432;
    int rr = r - g * 432;
    int o = rr >> 4;
    int4 cc = scoords[g * 16 + (rr & 15)];
    int nz = cc.y + o / 9 - 1, ny = cc.z + (o / 3) % 3 - 1, nx = cc.w + o % 3 - 1;
    int j = -1;
    if ((u32)nz < (u32)D1_ && (u32)ny < (u32)H_ && (u32)nx < (u32)W_)
      j = p.idx1[((size_t)(cc.x * D1_ + nz) * H_ + ny) * W_ + nx];
    p.nbr1[(size_t)(blockIdx.x * 4 + g) * 432 + rr] = j;
    if (j >= 0) atomicOr(&smask[g], 1u << o);
  }
  __syncthreads();
  if (t < 4) p.gmask1[blockIdx.x * 4 + t] = smask[t];
  float gr_[16], br_[16];
#pragma unroll
  for (int ks = 0; ks < 2; ++ks)
#pragma unroll
    for (int e = 0; e < 8; ++e) {
      int c = ks * 32 + kr * 8 + e;
      gr_[ks * 8 + e] = ggs[c];
      br_[ks * 8 + e] = bbs[c];
    }
  int base = blockBase + wg * 16;
  f32x4 acc0 = {0.f, 0.f, 0.f, 0.f};
  f32x4 acc1 = acc0, acc2 = acc0, acc3 = acc0;
  if (base < cnt1) {
    int pt = base + am;
    bool vpt = pt < cnt1;
    const int* np = p.nbrz1 + (size_t)pt * 3;
    int j0 = vpt ? np[0] : -1;
    int j1 = vpt ? np[1] : -1;
    int j2 = vpt ? np[2] : -1;
    bf16x8 r0[2], r1[2], r2[2];
    loadRawB16(p.xb0, j0, kr, r0);
    loadRawB16(p.xb0, j1, kr, r1);
    loadRawB16(p.xb0, j2, kr, r2);
    bf16x8 a[2];
    cvtB16(r0, j0, gr_, br_, a);
    mfma_step<2>(p.wfz1 + lane * 8, a, acc0, acc1, acc2, acc3);
    cvtB16(r1, j1, gr_, br_, a);
    mfma_step<2>(p.wfz1 + 4096 + lane * 8, a, acc0, acc1, acc2, acc3);
    cvtB16(r2, j2, gr_, br_, a);
    mfma_step<2>(p.wfz1 + 8192 + lane * 8, a, acc0, acc1, acc2, acc3);
    store_stats64(base, cnt1, am, kr, acc0, acc1, acc2, acc3, p.xb1, lsum, lss);
  }
  __syncthreads();
  if (t < 64) {
    flush_stats(t, blockIdx.x, p.stats + 512, lsum, lss);
    claim_ep(t, blockBase, cnt1, p.coords1, p.idx1, D1_, D2_, p.claim2, p.coords2, p.nbrz2,
             p.ctrl + 2, 0);
  }
}

// conv1 (a/b): 4 groups/block, wave-per-group, chunked 4-deep raw prefetch + inline BN
__global__ __launch_bounds__(256) void k_conv1(P p, const u16* __restrict__ xin,
                                               u16* __restrict__ xout,
                                               const u16* __restrict__ wf,
                                               const float* __restrict__ sIn,
                                               float* __restrict__ sOut,
                                               const float* __restrict__ gam,
                                               const float* __restrict__ bet) {
  const int cnt1 = p.ctrl[1];
  const int blockBase = blockIdx.x * 64;
  if (blockBase >= cnt1) return;
  __shared__ float lsum[64], lss[64], ggs[64], bbs[64];
  const int t = threadIdx.x;
  const int lane = t & 63, wg = t >> 6, am = lane & 15, kr = lane >> 4;
  if (t < 64) { lsum[t] = 0.f; lss[t] = 0.f; }
  bn_pre(sIn, cnt1, gam, bet, ggs, bbs, t);
  __syncthreads();
  float gr_[16], br_[16];
#pragma unroll
  for (int ks = 0; ks < 2; ++ks)
#pragma unroll
    for (int e = 0; e < 8; ++e) {
      int c = ks * 32 + kr * 8 + e;
      gr_[ks * 8 + e] = ggs[c];
      br_[ks * 8 + e] = bbs[c];
    }
  int base = blockBase + wg * 16;
  f32x4 acc0 = {0.f, 0.f, 0.f, 0.f};
  f32x4 acc1 = acc0, acc2 = acc0, acc3 = acc0;
  if (base < cnt1) {
    int g = blockIdx.x * 4 + wg;
    u32 mask = p.gmask1[g];
    const int* nb = p.nbr1 + (size_t)g * 432 + am;
    bf16x8 a[2];
    while (mask) {
      int os0 = __builtin_ctz(mask); mask &= mask - 1;
      int os1 = -1, os2 = -1, os3 = -1;
      if (mask) { os1 = __builtin_ctz(mask); mask &= mask - 1; }
      if (mask) { os2 = __builtin_ctz(mask); mask &= mask - 1; }
      if (mask) { os3 = __builtin_ctz(mask); mask &= mask - 1; }
      int j0 = nb[os0 * 16];
      int j1 = (os1 >= 0) ? nb[os1 * 16] : -1;
      int j2 = (os2 >= 0) ? nb[os2 * 16] : -1;
      int j3 = (os3 >= 0) ? nb[os3 * 16] : -1;
      bf16x8 r0[2], r1[2], r2[2], r3[2];
      loadRawB16(xin, j0, kr, r0);
      loadRawB16(xin, j1, kr, r1);
      loadRawB16(xin, j2, kr, r2);
      loadRawB16(xin, j3, kr, r3);
      cvtB16(r0, j0, gr_, br_, a);
      mfma_step<2>(wf + (size_t)os0 * 4096 + lane * 8, a, acc0, acc1, acc2, acc3);
      if (os1 >= 0) {
        cvtB16(r1, j1, gr_, br_, a);
        mfma_step<2>(wf + (size_t)os1 * 4096 + lane * 8, a, acc0, acc1, acc2, acc3);
      }
      if (os2 >= 0) {
        cvtB16(r2, j2, gr_, br_, a);
        mfma_step<2>(wf + (size_t)os2 * 4096 + lane * 8, a, acc0, acc1, acc2, acc3);
      }
      if (os3 >= 0) {
        cvtB16(r3, j3, gr_, br_, a);
        mfma_step<2>(wf + (size_t)os3 * 4096 + lane * 8, a, acc0, acc1, acc2, acc3);
      }
    }
    store_stats64(base, cnt1, am, kr, acc0, acc1, acc2, acc3, xout, lsum, lss);
  }
  __syncthreads();
  flush_stats(t, blockIdx.x, sOut, lsum, lss);
}

// convz2: BN3-inline, 3-tap full prefetch + stats4
__global__ __launch_bounds__(256) void k_convz2(P p) {
  const int cnt1 = p.ctrl[1];
  const int cnt2 = p.ctrl[2];
  const int blockBase = blockIdx.x * 64;
  if (blockBase >= cnt2) return;
  __shared__ float lsum[64], lss[64], ggs[64], bbs[64];
  const int t = threadIdx.x;
  const int lane = t & 63, wg = t >> 6, am = lane & 15, kr = lane >> 4;
  if (t < 64) { lsum[t] = 0.f; lss[t] = 0.f; }
  bn_pre(p.stats + 1536, cnt1, p.g3, p.b3, ggs, bbs, t);
  __syncthreads();
  float gr_[16], br_[16];
#pragma unroll
  for (int ks = 0; ks < 2; ++ks)
#pragma unroll
    for (int e = 0; e < 8; ++e) {
      int c = ks * 32 + kr * 8 + e;
      gr_[ks * 8 + e] = ggs[c];
      br_[ks * 8 + e] = bbs[c];
    }
  int base = blockBase + wg * 16;
  if (base < cnt2) {
    int pt = base + am;
    bool vpt = pt < cnt2;
    const int* np = p.nbrz2 + (size_t)pt * 3;
    int j0 = vpt ? np[0] : -1;
    int j1 = vpt ? np[1] : -1;
    int j2 = vpt ? np[2] : -1;
    bf16x8 r0[2], r1[2], r2[2];
    loadRawB16(p.xb3, j0, kr, r0);
    loadRawB16(p.xb3, j1, kr, r1);
    loadRawB16(p.xb3, j2, kr, r2);
    f32x4 acc0 = {0.f, 0.f, 0.f, 0.f};
    f32x4 acc1 = acc0, acc2 = acc0, acc3 = acc0;
    bf16x8 a[2];
    cvtB16(r0, j0, gr_, br_, a);
    mfma_step<2>(p.wfz2 + lane * 8, a, acc0, acc1, acc2, acc3);
    cvtB16(r1, j1, gr_, br_, a);
    mfma_step<2>(p.wfz2 + 4096 + lane * 8, a, acc0, acc1, acc2, acc3);
    cvtB16(r2, j2, gr_, br_, a);
    mfma_step<2>(p.wfz2 + 8192 + lane * 8, a, acc0, acc1, acc2, acc3);
    store_stats64(base, cnt2, am, kr, acc0, acc1, acc2, acc3, p.xb4, lsum, lss);
  }
  __syncthreads();
  flush_stats(t, blockIdx.x, p.stats + 2048, lsum, lss);
}

// dense output (reads bf16 xb4)
__global__ void k_s7(P p) {
  const int XQ = W_ / 4;
  const int cnt2 = p.ctrl[2];
  const long total = (long)B_ * 64 * D2_ * H_ * XQ;
  long tt = (long)blockIdx.x * 256 + threadIdx.x;
  if (tt >= total) return;
  const float* st = p.stats + 2048;
  int xq = (int)(tt % XQ);
  long row = tt / XQ;
  int y = (int)(row % H_);
  long r2 = row / H_;
  int oz = (int)(r2 % D2_);
  r2 /= D2_;
  int c = (int)(r2 & 63);
  int b = (int)(r2 >> 6);
  float s = 0.f, q = 0.f;
#pragma unroll
  for (int k = 0; k < 4; ++k) { s += st[k * 128 + c]; q += st[k * 128 + 64 + c]; }
  float cf = (float)(cnt2 > 0 ? cnt2 : 1);
  float mean = s / cf;
  float var = q / cf - mean * mean;
  float inv = rsqrtf(var + 1e-3f);
  float g = p.g4[c] * inv;
  float bb = p.b4[c] - mean * g;
  int pos = ((b * D2_ + oz) * H_ + y) * W_ + xq * 4;
  int4 ids = *(const int4*)(p.claim2 + pos);
  float4 v;
  v.x = (ids.x >= 0) ? fmaxf(bf2f(p.xb4[(size_t)ids.x * 64 + c]) * g + bb, 0.f) : 0.f;
  v.y = (ids.y >= 0) ? fmaxf(bf2f(p.xb4[(size_t)ids.y * 64 + c]) * g + bb, 0.f) : 0.f;
  v.z = (ids.z >= 0) ? fmaxf(bf2f(p.xb4[(size_t)ids.z * 64 + c]) * g + bb, 0.f) : 0.f;
  v.w = (ids.w >= 0) ? fmaxf(bf2f(p.xb4[(size_t)ids.w * 64 + c]) * g + bb, 0.f) : 0.f;
  *(float4*)(p.out + (size_t)row * W_ + xq * 4) = v;
}

extern "C" void kernel_launch(void* const* d_in, const int* in_sizes, int n_in,
                              void* d_out, int out_size, void* d_ws, size_t ws_size,
                              hipStream_t stream) {
  const int N = in_sizes[0] / 128;
  const int cap1 = 2 * N + 8;
  const int cap2 = 4 * N + 8;
  const int ng1 = (cap1 + 15) / 16;

  char* ws = (char*)d_ws;
  size_t off = 0;
  auto alloc = [&](size_t bytes) -> void* {
    size_t o = off;
    off = (off + bytes + 255) & ~(size_t)255;
    return (void*)(ws + o);
  };

  P p;
  p.ctrl = (int*)alloc(16);
  p.stats = (float*)alloc(2560 * 4);
  p.idx0 = (int*)alloc((size_t)B_ * D0_ * HW_ * 4);   // tagged; no pre-fill needed
  size_t fill_beg = off;
  p.idx1 = (int*)alloc((size_t)B_ * D1_ * HW_ * 4);
  p.claim2 = (int*)alloc((size_t)B_ * D2_ * HW_ * 4);
  size_t fill_end = off;
  p.nbr1 = (int*)alloc((size_t)(ng1 + 4) * 432 * 4);
  p.gmask1 = (u32*)alloc((size_t)(ng1 + 4) * 4);
  p.nbrz1 = (int*)alloc((size_t)cap1 * 3 * 4);
  p.nbrz2 = (int*)alloc((size_t)cap2 * 3 * 4);
  p.coords1 = (int*)alloc((size_t)cap1 * 4 * 4);
  p.coords2 = (int*)alloc((size_t)cap2 * 4 * 4);
  p.xb0 = (u16*)alloc((size_t)N * 64 * 2);
  p.xb1 = (u16*)alloc((size_t)cap1 * 64 * 2);
  p.xb2 = (u16*)alloc((size_t)cap1 * 64 * 2);
  p.xb3 = (u16*)alloc((size_t)cap1 * 64 * 2);
  p.xb4 = (u16*)alloc((size_t)cap2 * 64 * 2);
  p.fb = (u16*)alloc((size_t)N * 128 * 2);
  p.wf0 = (u16*)alloc((size_t)27 * 4 * 2048 * 2);
  p.wf1a = (u16*)alloc((size_t)27 * 2 * 2048 * 2);
  p.wf1b = (u16*)alloc((size_t)27 * 2 * 2048 * 2);
  p.wfz1 = (u16*)alloc((size_t)3 * 2 * 2048 * 2);
  p.wfz2 = (u16*)alloc((size_t)3 * 2 * 2048 * 2);

  p.feats = (const float*)d_in[0];
  p.coors = (const int*)d_in[1];
  p.w0 = (const float*)d_in[3];
  p.g0 = (const float*)d_in[4]; p.b0 = (const float*)d_in[5];
  p.wz1 = (const float*)d_in[6];
  p.g1 = (const float*)d_in[7]; p.b1 = (const float*)d_in[8];
  p.w1a = (const float*)d_in[9];
  p.g2 = (const float*)d_in[10]; p.b2 = (const float*)d_in[11];
  p.w1b = (const float*)d_in[12];
  p.g3 = (const float*)d_in[13]; p.b3 = (const float*)d_in[14];
  p.wz2 = (const float*)d_in[15];
  p.g4 = (const float*)d_in[16]; p.b4 = (const float*)d_in[17];
  p.out = (float*)d_out;
  p.fillp = (uint4*)(ws + fill_beg);
  p.N = N;
  p.nfill16 = (int)((fill_end - fill_beg) / 16);
  p.prepTotal = (long)N * 128 + 221184 + 110592 + 110592 + 12288 + 12288 + N;

  const int nb0 = (N + 63) / 64;
  const int nb1 = (cap1 + 63) / 64;
  const int nb2 = (cap2 + 63) / 64;
  const long outThreads = (long)B_ * 64 * D2_ * H_ * (W_ / 4);
  const long bootTotal = (long)p.nfill16 + 2563 + p.prepTotal;

  k_boot<<<dim3((unsigned)((bootTotal + 255) / 256)), 256, 0, stream>>>(p);
  k_conv0<<<dim3(nb0), 256, 0, stream>>>(p);
  k_convz1<<<dim3(nb1), 256, 0, stream>>>(p);
  k_conv1<<<dim3(nb1), 256, 0, stream>>>(p, p.xb1, p.xb2, p.wf1a, p.stats + 512,
                                         p.stats + 1024, p.g1, p.b1);
  k_conv1<<<dim3(nb1), 256, 0, stream>>>(p, p.xb2, p.xb3, p.wf1b, p.stats + 1024,
                                         p.stats + 1536, p.g2, p.b2);
  k_convz2<<<dim3(nb2), 256, 0, stream>>>(p);
  k_s7<<<dim3((unsigned)((outThreads + 255) / 256)), 256, 0, stream>>>(p);
}